// Round 31
// baseline (127.299 us; speedup 1.0000x reference)
//
#include <hip/hip_runtime.h>
#include <hip/hip_bf16.h>
#include <math.h>

#define DD 128
#define DH 64
#define BM 128
#define NTHR_G 512
#define NEDGE_B 242
#define SLOTS 64
#define MAXN_F (1.0f - 4e-3f)

typedef short s8v __attribute__((ext_vector_type(8)));   // 8 bf16 (4 VGPR)
typedef float f4v __attribute__((ext_vector_type(4)));   // MFMA accum

__device__ inline float wsum(float v) {
#pragma unroll
    for (int off = 32; off > 0; off >>= 1) v += __shfl_xor(v, off, 64);
    return v;
}
__device__ inline float gsum32(float v) {
#pragma unroll
    for (int off = 16; off > 0; off >>= 1) v += __shfl_xor(v, off, 64);
    return v;
}
__device__ inline unsigned short f2bf16(float x) {
    unsigned u = __float_as_uint(x);
    u += 0x7fffu + ((u >> 16) & 1u);   // RNE
    return (unsigned short)(u >> 16);
}
__device__ inline unsigned packbf(float a, float b) {
    return (unsigned)f2bf16(a) | ((unsigned)f2bf16(b) << 16);
}
__device__ inline float fatanh(float z) {
    return 0.5f * __logf(__fdividef(1.f + z, 1.f - z));
}
__device__ inline float ftanh(float y) {
    y = fminf(y, 10.f);
    float e = __expf(2.f * y);
    return __fdividef(e - 1.f, e + 1.f);
}

// ---- tiny one-shot: W fp32->bf16 pre-swizzled (blocks 0..7) + bias (blk 8)
__global__ __launch_bounds__(256) void wprep_k(
    const float* __restrict__ W, const float* __restrict__ bias,
    const float* __restrict__ atti, const float* __restrict__ attj,
    s8v* __restrict__ wbf, float* __restrict__ hbg, float* __restrict__ cst) {
    int s = blockIdx.x * 256 + threadIdx.x;
    if (s < 2048) {
        int row = s >> 4, ch = s & 15;
        const float4* W4 = reinterpret_cast<const float4*>(W);
        float4 f0 = W4[row * 32 + ch * 2];
        float4 f1 = W4[row * 32 + ch * 2 + 1];
        s8v hv;
        hv[0] = (short)f2bf16(f0.x); hv[1] = (short)f2bf16(f0.y);
        hv[2] = (short)f2bf16(f0.z); hv[3] = (short)f2bf16(f0.w);
        hv[4] = (short)f2bf16(f1.x); hv[5] = (short)f2bf16(f1.y);
        hv[6] = (short)f2bf16(f1.z); hv[7] = (short)f2bf16(f1.w);
        wbf[row * 16 + (ch ^ (row & 15))] = hv;
    }
    if (blockIdx.x == 8) {
        __shared__ float red[2];
        int tid = threadIdx.x;
        bool act = tid < 128;
        float b  = act ? bias[tid] : 0.f;
        float av_ = act ? atti[tid] : 0.f;
        float bv_ = act ? attj[tid] : 0.f;
        float s1 = wsum(b * b);
        if (act && (tid & 63) == 0) red[tid >> 6] = s1;
        __syncthreads();
        float S = red[0] + red[1];
        __syncthreads();
        float nb_ = fmaxf(sqrtf(S), 1e-15f);
        float e = tanhf(nb_) * b / nb_;
        float s2 = wsum(e * e);
        if (act && (tid & 63) == 0) red[tid >> 6] = s2;
        __syncthreads();
        float ne = fmaxf(sqrtf(red[0] + red[1]), 1e-15f);
        __syncthreads();
        if (ne > MAXN_F) e *= MAXN_F / ne;
        if (act) hbg[tid] = e;
        float s3 = wsum(e * e);
        if (act && (tid & 63) == 0) red[tid >> 6] = s3;
        __syncthreads();
        if (tid == 0) cst[0] = red[0] + red[1];
        float di = wsum(e * av_);
        float dj = wsum(e * bv_);
        if (act && (tid & 63) == 0) {
            int h = tid >> 6;
            cst[1 + h] = di;
            cst[3 + h] = dj;
        }
    }
}

// ---- fat kernel: blocks [0,ngemm) = MFMA gemm tile; rest = edge scatter ----
__global__ __launch_bounds__(NTHR_G) void gemm_edge_k(
    const float* __restrict__ x, const s8v* __restrict__ wbf,
    const float* __restrict__ hbg, const float* __restrict__ cst,
    const float* __restrict__ atti, const float* __restrict__ attj,
    const int* __restrict__ eidx, int* __restrict__ deg,
    int* __restrict__ slots,
    unsigned* __restrict__ xtb, float* __restrict__ ai, float* __restrict__ aj,
    int n, int E, int ngemm) {
    __shared__ short xl[BM * 128];    // 32 KB bf16 x tile
    __shared__ float sxq[BM];
    const int tid = threadIdx.x;
    if (blockIdx.x >= ngemm) {
        // ---------- edge-scatter partition (overlaps gemm blocks) ----------
        int eb = blockIdx.x - ngemm;
        for (int e = eb * NTHR_G + tid; e < E; e += NEDGE_B * NTHR_G) {
            int t = eidx[e], sv = eidx[E + e];
            int pos = atomicAdd(&deg[t], 1);
            if (pos < SLOTS) slots[(size_t)t * SLOTS + pos] = sv;
        }
        return;
    }
    const int row0 = blockIdx.x * BM;
    const int wv = tid >> 6;          // 0..7
    const int lane = tid & 63;
    const int l15 = lane & 15;
    const int g = lane >> 4;
    const float4* x4 = reinterpret_cast<const float4*>(x);
    s8v* xl8 = reinterpret_cast<s8v*>(xl);
#pragma unroll
    for (int i = 0; i < 4; ++i) {
        int s = tid + i * NTHR_G;
        int r = s >> 4, ch = s & 15;
        int grow = row0 + r;
        float4 f0 = make_float4(0.f, 0.f, 0.f, 0.f), f1 = f0;
        if (grow < n) {
            f0 = x4[(size_t)grow * 32 + ch * 2];
            f1 = x4[(size_t)grow * 32 + ch * 2 + 1];
        }
        s8v hv;
        hv[0] = (short)f2bf16(f0.x); hv[1] = (short)f2bf16(f0.y);
        hv[2] = (short)f2bf16(f0.z); hv[3] = (short)f2bf16(f0.w);
        hv[4] = (short)f2bf16(f1.x); hv[5] = (short)f2bf16(f1.y);
        hv[6] = (short)f2bf16(f1.z); hv[7] = (short)f2bf16(f1.w);
        xl8[r * 16 + (ch ^ (r & 15))] = hv;
        float px = f0.x * f0.x + f0.y * f0.y + f0.z * f0.z + f0.w * f0.w +
                   f1.x * f1.x + f1.y * f1.y + f1.z * f1.z + f1.w * f1.w;
#pragma unroll
        for (int off = 8; off > 0; off >>= 1) px += __shfl_xor(px, off, 16);
        if ((tid & 15) == 0) sxq[r] = px;
    }
    float y2v = cst[0];
    float Yi0 = cst[1], Yi1 = cst[2], Yj0 = cst[3], Yj1 = cst[4];
    float hbv[8], av[8], bv[8];
#pragma unroll
    for (int ct = 0; ct < 8; ++ct) {
        int c = ct * 16 + l15;
        hbv[ct] = hbg[c];
        av[ct] = atti[c];
        bv[ct] = attj[c];
    }
    __syncthreads();
    f4v acc[8];
#pragma unroll
    for (int ct = 0; ct < 8; ++ct) acc[ct] = (f4v){0.f, 0.f, 0.f, 0.f};
#pragma unroll
    for (int kc = 0; kc < 4; ++kc) {
        s8v a = xl8[(wv * 16 + l15) * 16 + ((kc * 4 + g) ^ l15)];
#pragma unroll
        for (int ct = 0; ct < 8; ++ct) {
            s8v b = wbf[(ct * 16 + l15) * 16 + ((kc * 4 + g) ^ l15)];
            acc[ct] = __builtin_amdgcn_mfma_f32_16x16x32_bf16(a, b, acc[ct], 0, 0, 0);
        }
    }
    float red[24];
#pragma unroll
    for (int reg = 0; reg < 4; ++reg) {
        float sm = 0.f, my = 0.f, d0 = 0.f, d1 = 0.f, f0 = 0.f, f1 = 0.f;
#pragma unroll
        for (int ct = 0; ct < 8; ++ct) {
            float v = acc[ct][reg];
            sm += v * v;
            my += v * hbv[ct];
            if (ct < 4) { d0 += v * av[ct]; f0 += v * bv[ct]; }
            else        { d1 += v * av[ct]; f1 += v * bv[ct]; }
        }
        red[reg * 6 + 0] = sm; red[reg * 6 + 1] = my;
        red[reg * 6 + 2] = d0; red[reg * 6 + 3] = d1;
        red[reg * 6 + 4] = f0; red[reg * 6 + 5] = f1;
    }
#pragma unroll
    for (int off = 8; off > 0; off >>= 1) {
#pragma unroll
        for (int j = 0; j < 24; ++j) red[j] += __shfl_xor(red[j], off, 16);
    }
#pragma unroll
    for (int reg = 0; reg < 4; ++reg) {
        int rr = wv * 16 + g * 4 + reg;
        int gr = row0 + rr;
        float Sx  = sxq[rr];
        float Sm  = red[reg * 6 + 0];
        float My  = red[reg * 6 + 1];
        float Di0 = red[reg * 6 + 2];
        float Di1 = red[reg * 6 + 3];
        float Dj0 = red[reg * 6 + 4];
        float Dj1 = red[reg * 6 + 5];
        float xn = fmaxf(sqrtf(Sx), 1e-15f);
        float mxn = fmaxf(sqrtf(Sm), 1e-15f);
        float art = fatanh(fminf(xn, 1.f - 1e-7f));
        float tn = ftanh(__fdividef(mxn, xn) * art);
        float rho = (Sm == 0.f) ? 0.f : __fdividef(tn, mxn);
        float pn = (Sm == 0.f) ? 0.f : tn;
        if (pn > MAXN_F) { rho *= MAXN_F / pn; pn = MAXN_F; }
        float X2 = pn * pn, XY = rho * My;
        float ca = 1.f + 2.f * XY + y2v;
        float cb = 1.f - X2;
        float dn = fmaxf(1.f + 2.f * XY + X2 * y2v, 1e-15f);
        float Sh = __fdividef(ca * ca * X2 + 2.f * ca * cb * XY + cb * cb * y2v,
                              dn * dn);
        float nraw = fmaxf(sqrtf(Sh), 1e-15f);
        float scp = 1.f, nh = nraw;
        if (nraw > MAXN_F) { scp = MAXN_F / nraw; nh = MAXN_F; }
        float gg = __fdividef(fatanh(fminf(nh, 1.f - 1e-7f)), nh);
        float gs = __fdividef(gg * scp, dn);
        float al = gs * ca * rho;
        float be = gs * cb;
        if (gr < n) {
#pragma unroll
            for (int ct = 0; ct < 4; ++ct) {
                xtb[(size_t)gr * DH + ct * 16 + l15] =
                    packbf(al * acc[ct][reg] + be * hbv[ct],
                           al * acc[ct + 4][reg] + be * hbv[ct + 4]);
            }
            if (l15 == 0) {
                reinterpret_cast<float2*>(ai)[gr] =
                    make_float2(al * Di0 + be * Yi0, al * Di1 + be * Yi1);
                reinterpret_cast<float2*>(aj)[gr] =
                    make_float2(al * Dj0 + be * Yj0, al * Dj1 + be * Yj1);
            }
        }
    }
}

// ---- fused softmax + aggregation + HypAct: 2 nodes/wave, packed weights --
__global__ __launch_bounds__(256) void agg_fused_k(
    const int* __restrict__ degv, const int* __restrict__ slots,
    const float* __restrict__ ai, const float* __restrict__ aj,
    const unsigned* __restrict__ xtb, float* __restrict__ out, int n) {
    const int wid = (blockIdx.x * 256 + threadIdx.x) >> 6;
    const int grp = (threadIdx.x >> 5) & 1;
    const int l = threadIdx.x & 31;
    const int base = threadIdx.x & 32;
    int t0 = wid * 2 + grp;
    bool valid = (t0 < n);
    int t = valid ? t0 : (n - 1);
    const int deg = min(degv[t], SLOTS);
    const int cnt = deg + 1;               // + self loop
    const size_t sbase = (size_t)t * SLOTS;
    int cnt_o = __shfl_xor(cnt, 32, 64);
    int jmax = max(cnt, cnt_o);            // wave-uniform
    float2 ait = reinterpret_cast<const float2*>(ai)[t];
    const float2* aj2 = reinterpret_cast<const float2*>(aj);
    float ux, uy;
    if (jmax <= 32) {
        int s_ = t;
        if (l < deg) s_ = slots[sbase + l];
        float e0 = 0.f, e1 = 0.f;
        if (l < cnt) {
            float2 av = aj2[s_];
            float a0 = ait.x + av.x; a0 = a0 < 0.f ? 0.2f * a0 : a0;
            float a1 = ait.y + av.y; a1 = a1 < 0.f ? 0.2f * a1 : a1;
            e0 = __expf(a0);
            e1 = __expf(a1);
        }
        float den0 = gsum32(e0), den1 = gsum32(e1);
        unsigned wpk = packbf(0.5f * __fdividef(e0, den0 + 1e-16f),
                              0.5f * __fdividef(e1, den1 + 1e-16f));
        float ax = 0.f, ay = 0.f;
        int jm2 = (jmax + 1) & ~1;
        for (int j = 0; j < jm2; j += 2) {
            int sA = __shfl(s_, base + j, 64);
            unsigned pA = __shfl((int)wpk, base + j, 64);
            int sB = __shfl(s_, base + j + 1, 64);
            unsigned pB = __shfl((int)wpk, base + j + 1, 64);
            float wA0 = __uint_as_float(pA << 16);
            float wA1 = __uint_as_float(pA & 0xffff0000u);
            float wB0 = __uint_as_float(pB << 16);
            float wB1 = __uint_as_float(pB & 0xffff0000u);
            uint2 vA = *reinterpret_cast<const uint2*>(
                xtb + (size_t)sA * DH + 2 * l);
            uint2 vB = *reinterpret_cast<const uint2*>(
                xtb + (size_t)sB * DH + 2 * l);
            ax += wA0 * __uint_as_float(vA.x << 16) +
                  wA1 * __uint_as_float(vA.x & 0xffff0000u) +
                  wB0 * __uint_as_float(vB.x << 16) +
                  wB1 * __uint_as_float(vB.x & 0xffff0000u);
            ay += wA0 * __uint_as_float(vA.y << 16) +
                  wA1 * __uint_as_float(vA.y & 0xffff0000u) +
                  wB0 * __uint_as_float(vB.y << 16) +
                  wB1 * __uint_as_float(vB.y & 0xffff0000u);
        }
        ux = ax; uy = ay;
    } else {
        float a0x = 0.f, a0y = 0.f, a1x = 0.f, a1y = 0.f;
        float den0 = 0.f, den1 = 0.f;
        int bmax = (jmax + 31) & ~31;
        for (int bs = 0; bs < bmax; bs += 32) {
            int idx = bs + l;
            int s = t;
            float e0 = 0.f, e1 = 0.f;
            if (idx < cnt) {
                s = (idx < deg) ? slots[sbase + idx] : t;
                float2 av = aj2[s];
                float a0 = ait.x + av.x; a0 = a0 < 0.f ? 0.2f * a0 : a0;
                float a1 = ait.y + av.y; a1 = a1 < 0.f ? 0.2f * a1 : a1;
                e0 = __expf(a0);
                e1 = __expf(a1);
            }
            den0 += e0;
            den1 += e1;
            for (int j = 0; j < 32 && bs + j < jmax; ++j) {
                int sj = __shfl(s, base + j, 64);
                float w0 = __shfl(e0, base + j, 64);
                float w1 = __shfl(e1, base + j, 64);
                if (bs + j < cnt) {
                    uint2 v = *reinterpret_cast<const uint2*>(
                        xtb + (size_t)sj * DH + 2 * l);
                    a0x += w0 * __uint_as_float(v.x << 16);
                    a1x += w1 * __uint_as_float(v.x & 0xffff0000u);
                    a0y += w0 * __uint_as_float(v.y << 16);
                    a1y += w1 * __uint_as_float(v.y & 0xffff0000u);
                }
            }
        }
        den0 = gsum32(den0);
        den1 = gsum32(den1);
        ux = 0.5f * (__fdividef(a0x, den0 + 1e-16f) +
                     __fdividef(a1x, den1 + 1e-16f));
        uy = 0.5f * (__fdividef(a0y, den0 + 1e-16f) +
                     __fdividef(a1y, den1 + 1e-16f));
    }
    float Su = gsum32(ux * ux + uy * uy);
    float nu = fmaxf(sqrtf(Su), 1e-15f);
    float the = ftanh(nu);
    float iv = __fdividef(the, nu);
    float ex = iv * ux, ey = iv * uy;
    float nh = the;
    if (the > MAXN_F) {
        float sc = MAXN_F / the;
        ex *= sc; ey *= sc; nh = MAXN_F;
    }
    float g = __fdividef(fatanh(fminf(nh, 1.f - 1e-7f)), fmaxf(nh, 1e-15f));
    float htx = g * ex, hty = g * ey;
    htx = htx < 0.f ? 0.01f * htx : htx;
    hty = hty < 0.f ? 0.01f * hty : hty;
    float St = gsum32(htx * htx + hty * hty);
    float nt = fmaxf(sqrtf(St), 1e-15f);
    float to = ftanh(nt);
    float ov = __fdividef(to, nt);
    float ox = ov * htx, oy = ov * hty;
    if (to > MAXN_F) { float sc = MAXN_F / to; ox *= sc; oy *= sc; }
    if (valid)
        reinterpret_cast<float2*>(out)[(size_t)t * 32 + l] = make_float2(ox, oy);
}

extern "C" void kernel_launch(void* const* d_in, const int* in_sizes, int n_in,
                              void* d_out, int out_size, void* d_ws, size_t ws_size,
                              hipStream_t stream) {
    const float* x    = (const float*)d_in[0];
    const int*   eidx = (const int*)d_in[1];
    const float* W    = (const float*)d_in[2];
    const float* bias = (const float*)d_in[3];
    const float* atti = (const float*)d_in[4];
    const float* attj = (const float*)d_in[5];
    float* out = (float*)d_out;

    const int n = in_sizes[0] / DD;  // 100000
    const int E = in_sizes[1] / 2;   // 600000
    const size_t nf = (size_t)n;

    unsigned* xtb = (unsigned*)d_ws;            // n*64 dwords (bf16 pairs)
    float* ai   = (float*)(xtb + nf * DH);      // 2n
    float* aj   = ai + 2 * nf;                  // 2n
    int* deg    = (int*)(aj + 2 * nf);          // n
    int* slots  = deg + nf;                     // n*64 (25.6 MB)
    s8v* wbf    = (s8v*)(slots + nf * SLOTS);   // 2048 chunks (32 KB)
    float* hbg  = (float*)(wbf + 2048);         // 128
    float* cst  = hbg + 128;                    // 5

    const int ngemm = (n + BM - 1) / BM;
    const int npair = (n + 1) / 2;     // node pairs (2 per wave)

    hipMemsetAsync(deg, 0, nf * sizeof(int), stream);
    wprep_k<<<9, 256, 0, stream>>>(W, bias, atti, attj, wbf, hbg, cst);
    gemm_edge_k<<<ngemm + NEDGE_B, NTHR_G, 0, stream>>>(
        x, wbf, hbg, cst, atti, attj, eidx, deg, slots, xtb, ai, aj, n, E, ngemm);
    agg_fused_k<<<(npair + 3) / 4, 256, 0, stream>>>(deg, slots, ai, aj, xtb,
                                                     out, n);
}

// Round 32
// 111.807 us; speedup vs baseline: 1.1386x; 1.1386x over previous
//
#include <hip/hip_runtime.h>
#include <hip/hip_bf16.h>
#include <math.h>

#define DD 128
#define DH 64
#define BM 128
#define NTHR_G 512
#define NEDGE_B 196
#define SLOTS 64
#define MAXN_F (1.0f - 4e-3f)

typedef short s8v __attribute__((ext_vector_type(8)));   // 8 bf16 (4 VGPR)
typedef float f4v __attribute__((ext_vector_type(4)));   // MFMA accum

__device__ inline float wsum(float v) {
#pragma unroll
    for (int off = 32; off > 0; off >>= 1) v += __shfl_xor(v, off, 64);
    return v;
}
__device__ inline float gsum32(float v) {
#pragma unroll
    for (int off = 16; off > 0; off >>= 1) v += __shfl_xor(v, off, 64);
    return v;
}
__device__ inline unsigned short f2bf16(float x) {
    unsigned u = __float_as_uint(x);
    u += 0x7fffu + ((u >> 16) & 1u);   // RNE
    return (unsigned short)(u >> 16);
}
__device__ inline unsigned packbf(float a, float b) {
    return (unsigned)f2bf16(a) | ((unsigned)f2bf16(b) << 16);
}
__device__ inline float fatanh(float z) {
    return 0.5f * __logf(__fdividef(1.f + z, 1.f - z));
}
__device__ inline float ftanh(float y) {
    y = fminf(y, 10.f);
    float e = __expf(2.f * y);
    return __fdividef(e - 1.f, e + 1.f);
}

// ---- tiny one-shot: W fp32->bf16 pre-swizzled (blocks 0..7) + bias (blk 8)
__global__ __launch_bounds__(256) void wprep_k(
    const float* __restrict__ W, const float* __restrict__ bias,
    const float* __restrict__ atti, const float* __restrict__ attj,
    s8v* __restrict__ wbf, float* __restrict__ hbg, float* __restrict__ cst) {
    int s = blockIdx.x * 256 + threadIdx.x;
    if (s < 2048) {
        int row = s >> 4, ch = s & 15;
        const float4* W4 = reinterpret_cast<const float4*>(W);
        float4 f0 = W4[row * 32 + ch * 2];
        float4 f1 = W4[row * 32 + ch * 2 + 1];
        s8v hv;
        hv[0] = (short)f2bf16(f0.x); hv[1] = (short)f2bf16(f0.y);
        hv[2] = (short)f2bf16(f0.z); hv[3] = (short)f2bf16(f0.w);
        hv[4] = (short)f2bf16(f1.x); hv[5] = (short)f2bf16(f1.y);
        hv[6] = (short)f2bf16(f1.z); hv[7] = (short)f2bf16(f1.w);
        wbf[row * 16 + (ch ^ (row & 15))] = hv;
    }
    if (blockIdx.x == 8) {
        __shared__ float red[2];
        int tid = threadIdx.x;
        bool act = tid < 128;
        float b  = act ? bias[tid] : 0.f;
        float av_ = act ? atti[tid] : 0.f;
        float bv_ = act ? attj[tid] : 0.f;
        float s1 = wsum(b * b);
        if (act && (tid & 63) == 0) red[tid >> 6] = s1;
        __syncthreads();
        float S = red[0] + red[1];
        __syncthreads();
        float nb_ = fmaxf(sqrtf(S), 1e-15f);
        float e = tanhf(nb_) * b / nb_;
        float s2 = wsum(e * e);
        if (act && (tid & 63) == 0) red[tid >> 6] = s2;
        __syncthreads();
        float ne = fmaxf(sqrtf(red[0] + red[1]), 1e-15f);
        __syncthreads();
        if (ne > MAXN_F) e *= MAXN_F / ne;
        if (act) hbg[tid] = e;
        float s3 = wsum(e * e);
        if (act && (tid & 63) == 0) red[tid >> 6] = s3;
        __syncthreads();
        if (tid == 0) cst[0] = red[0] + red[1];
        float di = wsum(e * av_);
        float dj = wsum(e * bv_);
        if (act && (tid & 63) == 0) {
            int h = tid >> 6;
            cst[1 + h] = di;
            cst[3 + h] = dj;
        }
    }
}

// ---- fat kernel: blocks [0,ngemm) = MFMA gemm tile; rest = edge scatter ----
__global__ __launch_bounds__(NTHR_G) void gemm_edge_k(
    const float* __restrict__ x, const s8v* __restrict__ wbf,
    const float* __restrict__ hbg, const float* __restrict__ cst,
    const float* __restrict__ atti, const float* __restrict__ attj,
    const int* __restrict__ eidx, int* __restrict__ deg,
    int* __restrict__ slots,
    unsigned* __restrict__ xtb, float* __restrict__ ai, float* __restrict__ aj,
    int n, int E, int ngemm) {
    __shared__ short xl[BM * 128];    // 32 KB bf16 x tile
    __shared__ float sxq[BM];
    const int tid = threadIdx.x;
    if (blockIdx.x >= ngemm) {
        // ---------- edge-scatter partition (overlaps gemm blocks) ----------
        int eb = blockIdx.x - ngemm;
        for (int e = eb * NTHR_G + tid; e < E; e += NEDGE_B * NTHR_G) {
            int t = eidx[e], sv = eidx[E + e];
            int pos = atomicAdd(&deg[t], 1);
            if (pos < SLOTS) slots[(size_t)t * SLOTS + pos] = sv;
        }
        return;
    }
    const int row0 = blockIdx.x * BM;
    const int wv = tid >> 6;          // 0..7
    const int lane = tid & 63;
    const int l15 = lane & 15;
    const int g = lane >> 4;
    const float4* x4 = reinterpret_cast<const float4*>(x);
    s8v* xl8 = reinterpret_cast<s8v*>(xl);
#pragma unroll
    for (int i = 0; i < 4; ++i) {
        int s = tid + i * NTHR_G;
        int r = s >> 4, ch = s & 15;
        int grow = row0 + r;
        float4 f0 = make_float4(0.f, 0.f, 0.f, 0.f), f1 = f0;
        if (grow < n) {
            f0 = x4[(size_t)grow * 32 + ch * 2];
            f1 = x4[(size_t)grow * 32 + ch * 2 + 1];
        }
        s8v hv;
        hv[0] = (short)f2bf16(f0.x); hv[1] = (short)f2bf16(f0.y);
        hv[2] = (short)f2bf16(f0.z); hv[3] = (short)f2bf16(f0.w);
        hv[4] = (short)f2bf16(f1.x); hv[5] = (short)f2bf16(f1.y);
        hv[6] = (short)f2bf16(f1.z); hv[7] = (short)f2bf16(f1.w);
        xl8[r * 16 + (ch ^ (r & 15))] = hv;
        float px = f0.x * f0.x + f0.y * f0.y + f0.z * f0.z + f0.w * f0.w +
                   f1.x * f1.x + f1.y * f1.y + f1.z * f1.z + f1.w * f1.w;
#pragma unroll
        for (int off = 8; off > 0; off >>= 1) px += __shfl_xor(px, off, 16);
        if ((tid & 15) == 0) sxq[r] = px;
    }
    float y2v = cst[0];
    float Yi0 = cst[1], Yi1 = cst[2], Yj0 = cst[3], Yj1 = cst[4];
    float hbv[8], av[8], bv[8];
#pragma unroll
    for (int ct = 0; ct < 8; ++ct) {
        int c = ct * 16 + l15;
        hbv[ct] = hbg[c];
        av[ct] = atti[c];
        bv[ct] = attj[c];
    }
    __syncthreads();
    f4v acc[8];
#pragma unroll
    for (int ct = 0; ct < 8; ++ct) acc[ct] = (f4v){0.f, 0.f, 0.f, 0.f};
#pragma unroll
    for (int kc = 0; kc < 4; ++kc) {
        s8v a = xl8[(wv * 16 + l15) * 16 + ((kc * 4 + g) ^ l15)];
#pragma unroll
        for (int ct = 0; ct < 8; ++ct) {
            s8v b = wbf[(ct * 16 + l15) * 16 + ((kc * 4 + g) ^ l15)];
            acc[ct] = __builtin_amdgcn_mfma_f32_16x16x32_bf16(a, b, acc[ct], 0, 0, 0);
        }
    }
    float red[24];
#pragma unroll
    for (int reg = 0; reg < 4; ++reg) {
        float sm = 0.f, my = 0.f, d0 = 0.f, d1 = 0.f, f0 = 0.f, f1 = 0.f;
#pragma unroll
        for (int ct = 0; ct < 8; ++ct) {
            float v = acc[ct][reg];
            sm += v * v;
            my += v * hbv[ct];
            if (ct < 4) { d0 += v * av[ct]; f0 += v * bv[ct]; }
            else        { d1 += v * av[ct]; f1 += v * bv[ct]; }
        }
        red[reg * 6 + 0] = sm; red[reg * 6 + 1] = my;
        red[reg * 6 + 2] = d0; red[reg * 6 + 3] = d1;
        red[reg * 6 + 4] = f0; red[reg * 6 + 5] = f1;
    }
#pragma unroll
    for (int off = 8; off > 0; off >>= 1) {
#pragma unroll
        for (int j = 0; j < 24; ++j) red[j] += __shfl_xor(red[j], off, 16);
    }
#pragma unroll
    for (int reg = 0; reg < 4; ++reg) {
        int rr = wv * 16 + g * 4 + reg;
        int gr = row0 + rr;
        float Sx  = sxq[rr];
        float Sm  = red[reg * 6 + 0];
        float My  = red[reg * 6 + 1];
        float Di0 = red[reg * 6 + 2];
        float Di1 = red[reg * 6 + 3];
        float Dj0 = red[reg * 6 + 4];
        float Dj1 = red[reg * 6 + 5];
        float xn = fmaxf(sqrtf(Sx), 1e-15f);
        float mxn = fmaxf(sqrtf(Sm), 1e-15f);
        float art = fatanh(fminf(xn, 1.f - 1e-7f));
        float tn = ftanh(__fdividef(mxn, xn) * art);
        float rho = (Sm == 0.f) ? 0.f : __fdividef(tn, mxn);
        float pn = (Sm == 0.f) ? 0.f : tn;
        if (pn > MAXN_F) { rho *= MAXN_F / pn; pn = MAXN_F; }
        float X2 = pn * pn, XY = rho * My;
        float ca = 1.f + 2.f * XY + y2v;
        float cb = 1.f - X2;
        float dn = fmaxf(1.f + 2.f * XY + X2 * y2v, 1e-15f);
        float Sh = __fdividef(ca * ca * X2 + 2.f * ca * cb * XY + cb * cb * y2v,
                              dn * dn);
        float nraw = fmaxf(sqrtf(Sh), 1e-15f);
        float scp = 1.f, nh = nraw;
        if (nraw > MAXN_F) { scp = MAXN_F / nraw; nh = MAXN_F; }
        float gg = __fdividef(fatanh(fminf(nh, 1.f - 1e-7f)), nh);
        float gs = __fdividef(gg * scp, dn);
        float al = gs * ca * rho;
        float be = gs * cb;
        if (gr < n) {
#pragma unroll
            for (int ct = 0; ct < 4; ++ct) {
                xtb[(size_t)gr * DH + ct * 16 + l15] =
                    packbf(al * acc[ct][reg] + be * hbv[ct],
                           al * acc[ct + 4][reg] + be * hbv[ct + 4]);
            }
            if (l15 == 0) {
                reinterpret_cast<float2*>(ai)[gr] =
                    make_float2(al * Di0 + be * Yi0, al * Di1 + be * Yi1);
                reinterpret_cast<float2*>(aj)[gr] =
                    make_float2(al * Dj0 + be * Yj0, al * Dj1 + be * Yj1);
            }
        }
    }
}

// ---- fused softmax + aggregation + HypAct: 2 nodes/wave, packed weights --
__global__ __launch_bounds__(256) void agg_fused_k(
    const int* __restrict__ degv, const int* __restrict__ slots,
    const float* __restrict__ ai, const float* __restrict__ aj,
    const unsigned* __restrict__ xtb, float* __restrict__ out, int n) {
    const int wid = (blockIdx.x * 256 + threadIdx.x) >> 6;
    const int grp = (threadIdx.x >> 5) & 1;
    const int l = threadIdx.x & 31;
    const int base = threadIdx.x & 32;
    int t0 = wid * 2 + grp;
    bool valid = (t0 < n);
    int t = valid ? t0 : (n - 1);
    const int deg = min(degv[t], SLOTS);
    const int cnt = deg + 1;               // + self loop
    const size_t sbase = (size_t)t * SLOTS;
    int cnt_o = __shfl_xor(cnt, 32, 64);
    int jmax = max(cnt, cnt_o);            // wave-uniform
    float2 ait = reinterpret_cast<const float2*>(ai)[t];
    const float2* aj2 = reinterpret_cast<const float2*>(aj);
    float ux, uy;
    if (jmax <= 32) {
        int s_ = t;
        if (l < deg) s_ = slots[sbase + l];
        float e0 = 0.f, e1 = 0.f;
        if (l < cnt) {
            float2 av = aj2[s_];
            float a0 = ait.x + av.x; a0 = a0 < 0.f ? 0.2f * a0 : a0;
            float a1 = ait.y + av.y; a1 = a1 < 0.f ? 0.2f * a1 : a1;
            e0 = __expf(a0);
            e1 = __expf(a1);
        }
        float den0 = gsum32(e0), den1 = gsum32(e1);
        unsigned wpk = packbf(0.5f * __fdividef(e0, den0 + 1e-16f),
                              0.5f * __fdividef(e1, den1 + 1e-16f));
        float ax = 0.f, ay = 0.f;
        int jm2 = (jmax + 1) & ~1;
        for (int j = 0; j < jm2; j += 2) {
            int sA = __shfl(s_, base + j, 64);
            unsigned pA = __shfl((int)wpk, base + j, 64);
            int sB = __shfl(s_, base + j + 1, 64);
            unsigned pB = __shfl((int)wpk, base + j + 1, 64);
            float wA0 = __uint_as_float(pA << 16);
            float wA1 = __uint_as_float(pA & 0xffff0000u);
            float wB0 = __uint_as_float(pB << 16);
            float wB1 = __uint_as_float(pB & 0xffff0000u);
            uint2 vA = *reinterpret_cast<const uint2*>(
                xtb + (size_t)sA * DH + 2 * l);
            uint2 vB = *reinterpret_cast<const uint2*>(
                xtb + (size_t)sB * DH + 2 * l);
            ax += wA0 * __uint_as_float(vA.x << 16) +
                  wA1 * __uint_as_float(vA.x & 0xffff0000u) +
                  wB0 * __uint_as_float(vB.x << 16) +
                  wB1 * __uint_as_float(vB.x & 0xffff0000u);
            ay += wA0 * __uint_as_float(vA.y << 16) +
                  wA1 * __uint_as_float(vA.y & 0xffff0000u) +
                  wB0 * __uint_as_float(vB.y << 16) +
                  wB1 * __uint_as_float(vB.y & 0xffff0000u);
        }
        ux = ax; uy = ay;
    } else {
        float a0x = 0.f, a0y = 0.f, a1x = 0.f, a1y = 0.f;
        float den0 = 0.f, den1 = 0.f;
        int bmax = (jmax + 31) & ~31;
        for (int bs = 0; bs < bmax; bs += 32) {
            int idx = bs + l;
            int s = t;
            float e0 = 0.f, e1 = 0.f;
            if (idx < cnt) {
                s = (idx < deg) ? slots[sbase + idx] : t;
                float2 av = aj2[s];
                float a0 = ait.x + av.x; a0 = a0 < 0.f ? 0.2f * a0 : a0;
                float a1 = ait.y + av.y; a1 = a1 < 0.f ? 0.2f * a1 : a1;
                e0 = __expf(a0);
                e1 = __expf(a1);
            }
            den0 += e0;
            den1 += e1;
            for (int j = 0; j < 32 && bs + j < jmax; ++j) {
                int sj = __shfl(s, base + j, 64);
                float w0 = __shfl(e0, base + j, 64);
                float w1 = __shfl(e1, base + j, 64);
                if (bs + j < cnt) {
                    uint2 v = *reinterpret_cast<const uint2*>(
                        xtb + (size_t)sj * DH + 2 * l);
                    a0x += w0 * __uint_as_float(v.x << 16);
                    a1x += w1 * __uint_as_float(v.x & 0xffff0000u);
                    a0y += w0 * __uint_as_float(v.y << 16);
                    a1y += w1 * __uint_as_float(v.y & 0xffff0000u);
                }
            }
        }
        den0 = gsum32(den0);
        den1 = gsum32(den1);
        ux = 0.5f * (__fdividef(a0x, den0 + 1e-16f) +
                     __fdividef(a1x, den1 + 1e-16f));
        uy = 0.5f * (__fdividef(a0y, den0 + 1e-16f) +
                     __fdividef(a1y, den1 + 1e-16f));
    }
    float Su = gsum32(ux * ux + uy * uy);
    float nu = fmaxf(sqrtf(Su), 1e-15f);
    float the = ftanh(nu);
    float iv = __fdividef(the, nu);
    float ex = iv * ux, ey = iv * uy;
    float nh = the;
    if (the > MAXN_F) {
        float sc = MAXN_F / the;
        ex *= sc; ey *= sc; nh = MAXN_F;
    }
    float g = __fdividef(fatanh(fminf(nh, 1.f - 1e-7f)), fmaxf(nh, 1e-15f));
    float htx = g * ex, hty = g * ey;
    htx = htx < 0.f ? 0.01f * htx : htx;
    hty = hty < 0.f ? 0.01f * hty : hty;
    float St = gsum32(htx * htx + hty * hty);
    float nt = fmaxf(sqrtf(St), 1e-15f);
    float to = ftanh(nt);
    float ov = __fdividef(to, nt);
    float ox = ov * htx, oy = ov * hty;
    if (to > MAXN_F) { float sc = MAXN_F / to; ox *= sc; oy *= sc; }
    if (valid)
        reinterpret_cast<float2*>(out)[(size_t)t * 32 + l] = make_float2(ox, oy);
}

extern "C" void kernel_launch(void* const* d_in, const int* in_sizes, int n_in,
                              void* d_out, int out_size, void* d_ws, size_t ws_size,
                              hipStream_t stream) {
    const float* x    = (const float*)d_in[0];
    const int*   eidx = (const int*)d_in[1];
    const float* W    = (const float*)d_in[2];
    const float* bias = (const float*)d_in[3];
    const float* atti = (const float*)d_in[4];
    const float* attj = (const float*)d_in[5];
    float* out = (float*)d_out;

    const int n = in_sizes[0] / DD;  // 100000
    const int E = in_sizes[1] / 2;   // 600000
    const size_t nf = (size_t)n;

    unsigned* xtb = (unsigned*)d_ws;            // n*64 dwords (bf16 pairs)
    float* ai   = (float*)(xtb + nf * DH);      // 2n
    float* aj   = ai + 2 * nf;                  // 2n
    int* deg    = (int*)(aj + 2 * nf);          // n
    int* slots  = deg + nf;                     // n*64 (25.6 MB)
    s8v* wbf    = (s8v*)(slots + nf * SLOTS);   // 2048 chunks (32 KB)
    float* hbg  = (float*)(wbf + 2048);         // 128
    float* cst  = hbg + 128;                    // 5

    const int ngemm = (n + BM - 1) / BM;
    const int npair = (n + 1) / 2;     // node pairs (2 per wave)

    hipMemsetAsync(deg, 0, nf * sizeof(int), stream);
    wprep_k<<<9, 256, 0, stream>>>(W, bias, atti, attj, wbf, hbg, cst);
    gemm_edge_k<<<ngemm + NEDGE_B, NTHR_G, 0, stream>>>(
        x, wbf, hbg, cst, atti, attj, eidx, deg, slots, xtb, ai, aj, n, E, ngemm);
    agg_fused_k<<<(npair + 3) / 4, 256, 0, stream>>>(deg, slots, ai, aj, xtb,
                                                     out, n);
}